// Round 4
// baseline (1585.167 us; speedup 1.0000x reference)
//
#include <hip/hip_runtime.h>

// ---------------------------------------------------------------------------
// PiNet: 2x GCNConv + a2^T a2 readout + linear + softmax
// N=100000, E=3200000, D0=128, D1=D2=64, OUT=10
// R3: 2-pass bucketed CSR build (no full-range scatter, no global hist):
//     bucket by dst>>8 -> per-bucket LDS count/scan/place. Writes stay in
//     small L2-resident windows (write amp ~1x vs 15x in R2's scatter).
// ---------------------------------------------------------------------------

#define BUCKET_SHIFT 8
#define BUCKET_SZ 256
#define CAP 12288  // per-bucket edge capacity (mean 8192, sigma ~90)

// B1: bin edges by dst bucket. bedges[b*CAP+i] = (src, dst&255)
__global__ void bucket_scatter(const int* __restrict__ src, const int* __restrict__ dst,
                               int* __restrict__ bcnt, uint2* __restrict__ bedges, int E) {
    int e = blockIdx.x * blockDim.x + threadIdx.x;
    if (e < E) {
        int d = dst[e];
        int b = d >> BUCKET_SHIFT;
        int pos = atomicAdd(&bcnt[b], 1);
        if (pos < CAP) bedges[(size_t)b * CAP + pos] = make_uint2((unsigned)src[e], (unsigned)(d & (BUCKET_SZ - 1)));
    }
}

// B2: per-bucket histogram + local exclusive scan. Emits counts, dinv,
// rowptr (local prefix, global offset added later), btot[b].
__global__ __launch_bounds__(256) void bucket_count_scan(const int* __restrict__ bcnt,
                                                         const uint2* __restrict__ bedges,
                                                         int* __restrict__ counts,
                                                         float* __restrict__ dinv,
                                                         int* __restrict__ rowptr,
                                                         int* __restrict__ btot, int N) {
    __shared__ int lcnt[BUCKET_SZ];
    __shared__ int sc[BUCKET_SZ];
    const int b   = blockIdx.x;
    const int tid = threadIdx.x;
    lcnt[tid] = 0;
    __syncthreads();
    const int cnt = min(bcnt[b], CAP);
    for (int i = tid; i < cnt; i += 256)
        atomicAdd(&lcnt[(int)bedges[(size_t)b * CAP + i].y], 1);
    __syncthreads();
    int c = lcnt[tid];
    sc[tid] = c;
    __syncthreads();
    for (int off = 1; off < BUCKET_SZ; off <<= 1) {
        int t = (tid >= off) ? sc[tid - off] : 0;
        __syncthreads();
        sc[tid] += t;
        __syncthreads();
    }
    int n = (b << BUCKET_SHIFT) + tid;
    if (n < N) {
        counts[n] = c;
        dinv[n]   = rsqrtf((float)c + 1.0f);  // +1 self-loop
        rowptr[n] = sc[tid] - c;              // local exclusive prefix
    }
    if (tid == BUCKET_SZ - 1) btot[b] = sc[tid];
}

// B2b: exclusive scan of bucket totals (nb <= 512), in place, one block of 512.
__global__ void scan_btot(int* __restrict__ btot, int nb) {
    __shared__ int sh[512];
    const int tid = threadIdx.x;
    int v = (tid < nb) ? btot[tid] : 0;
    sh[tid] = v;
    __syncthreads();
    for (int off = 1; off < 512; off <<= 1) {
        int t = (tid >= off) ? sh[tid - off] : 0;
        __syncthreads();
        sh[tid] += t;
        __syncthreads();
    }
    if (tid < nb) btot[tid] = sh[tid] - v;  // exclusive
}

// B3: finalize rowptr/rowend (add bucket offset) and place src ids into the
// bucket's contiguous ssorted window via LDS cursors.
__global__ __launch_bounds__(256) void bucket_place(const int* __restrict__ bcnt,
                                                    const uint2* __restrict__ bedges,
                                                    const int* __restrict__ btot,
                                                    const int* __restrict__ counts,
                                                    int* __restrict__ rowptr,
                                                    int* __restrict__ rowend,
                                                    int* __restrict__ ssorted, int N) {
    __shared__ int lcur[BUCKET_SZ];
    const int b     = blockIdx.x;
    const int tid   = threadIdx.x;
    const int s_off = btot[b];
    int n  = (b << BUCKET_SHIFT) + tid;
    int lp = 0;
    if (n < N) {
        lp = rowptr[n];
        int c = counts[n];
        rowptr[n] = s_off + lp;
        rowend[n] = s_off + lp + c;
    }
    lcur[tid] = lp;
    __syncthreads();
    const int cnt = min(bcnt[b], CAP);
    for (int i = tid; i < cnt; i += 256) {
        uint2 e = bedges[(size_t)b * CAP + i];
        int pos = atomicAdd(&lcur[(int)e.y], 1);
        ssorted[s_off + pos] = (int)e.x;
    }
}

// ---------------------------------------------------------------------------
// Register-tiled GEMM: H[n][c] = sum_k A[n][k]*W[k][c], c in [0,64).
// 64 nodes x 64 cols per 256-thread block; each thread computes 4 nodes x 4 cols.
// ---------------------------------------------------------------------------
template <int K>
__global__ __launch_bounds__(256) void gemm_tiled(const float* __restrict__ A,
                                                  const float* __restrict__ W,
                                                  float* __restrict__ H, int N) {
    constexpr int KC = 32;
    __shared__ float xs[64][KC + 4];
    __shared__ float ws[KC][64];
    const int tid  = threadIdx.x;
    const int tx   = tid & 15;
    const int ty   = tid >> 4;
    const int base = blockIdx.x * 64;

    float acc[4][4] = {{0.f}};

    for (int kc = 0; kc < K; kc += KC) {
        for (int idx = tid; idx < 512; idx += 256) {
            int node = idx >> 3, k4 = idx & 7;
            int n = base + node;
            float4 v = make_float4(0.f, 0.f, 0.f, 0.f);
            if (n < N) v = *(const float4*)&A[(long long)n * K + kc + k4 * 4];
            *(float4*)&xs[node][k4 * 4] = v;
        }
        for (int idx = tid; idx < 512; idx += 256) {
            int k = idx >> 4, c4 = idx & 15;
            *(float4*)&ws[k][c4 * 4] = *(const float4*)&W[(long long)(kc + k) * 64 + c4 * 4];
        }
        __syncthreads();

#pragma unroll
        for (int k = 0; k < KC; k += 4) {
            float4 xv[4], wv[4];
#pragma unroll
            for (int i = 0; i < 4; ++i) xv[i] = *(const float4*)&xs[ty * 4 + i][k];
#pragma unroll
            for (int j = 0; j < 4; ++j) wv[j] = *(const float4*)&ws[k + j][tx * 4];
#pragma unroll
            for (int i = 0; i < 4; ++i) {
                float xi[4] = {xv[i].x, xv[i].y, xv[i].z, xv[i].w};
#pragma unroll
                for (int j = 0; j < 4; ++j) {
                    acc[i][0] += xi[j] * wv[j].x;
                    acc[i][1] += xi[j] * wv[j].y;
                    acc[i][2] += xi[j] * wv[j].z;
                    acc[i][3] += xi[j] * wv[j].w;
                }
            }
        }
        __syncthreads();
    }

#pragma unroll
    for (int i = 0; i < 4; ++i) {
        int n = base + ty * 4 + i;
        if (n < N) {
            float4 r = make_float4(acc[i][0], acc[i][1], acc[i][2], acc[i][3]);
            *(float4*)&H[(long long)n * 64 + tx * 4] = r;
        }
    }
}

// CSR aggregation, fused bias + self-loop. One wave per node.
__global__ void agg_csr(const int* __restrict__ rowptr, const int* __restrict__ endptr,
                        const int* __restrict__ ssorted, const float* __restrict__ dinv,
                        const float* __restrict__ H, const float* __restrict__ bias,
                        float* __restrict__ out, int N) {
    const int wid  = (int)(((long long)blockIdx.x * blockDim.x + threadIdx.x) >> 6);
    if (wid >= N) return;
    const int lane = threadIdx.x & 63;
    const int g    = lane >> 4;
    const int fl   = lane & 15;
    const float4* __restrict__ Hv = (const float4*)H;

    const int   n   = wid;
    const float dn  = dinv[n];
    const int   beg = rowptr[n];
    const int   end = endptr[n];

    float4 acc = make_float4(0.f, 0.f, 0.f, 0.f);
    for (int e = beg + g; e < end; e += 4) {
        int    s  = ssorted[e];
        float  w  = dinv[s] * dn;
        float4 hv = Hv[(long long)s * 16 + fl];
        acc.x += w * hv.x; acc.y += w * hv.y; acc.z += w * hv.z; acc.w += w * hv.w;
    }
    acc.x += __shfl_xor(acc.x, 16); acc.y += __shfl_xor(acc.y, 16);
    acc.z += __shfl_xor(acc.z, 16); acc.w += __shfl_xor(acc.w, 16);
    acc.x += __shfl_xor(acc.x, 32); acc.y += __shfl_xor(acc.y, 32);
    acc.z += __shfl_xor(acc.z, 32); acc.w += __shfl_xor(acc.w, 32);

    if (g == 0) {
        float4 selfv = Hv[(long long)n * 16 + fl];
        float4 bv    = ((const float4*)bias)[fl];
        float  w0    = dn * dn;
        float4 res;
        res.x = bv.x + w0 * selfv.x + acc.x;
        res.y = bv.y + w0 * selfv.y + acc.y;
        res.z = bv.z + w0 * selfv.z + acc.z;
        res.w = bv.w + w0 * selfv.w + acc.w;
        ((float4*)out)[(long long)n * 16 + fl] = res;
    }
}

// h64[r][c] += sum_n A2[n][r] * A2[n][c]
__global__ void outer_reduce(const float* __restrict__ A2, float* __restrict__ h64, int N) {
    __shared__ float rows[8][64];
    const int tid = threadIdx.x;
    const int col = tid & 63;
    const int rg  = tid >> 6;
    float acc[16];
#pragma unroll
    for (int i = 0; i < 16; ++i) acc[i] = 0.f;

    int npb   = (N + gridDim.x - 1) / gridDim.x;
    int start = blockIdx.x * npb;
    int end   = min(start + npb, N);
    for (int nb = start; nb < end; nb += 8) {
        int cnt = min(8, end - nb);
        __syncthreads();
        for (int idx = tid; idx < cnt * 64; idx += 256)
            rows[idx >> 6][idx & 63] = A2[(long long)(nb + (idx >> 6)) * 64 + (idx & 63)];
        __syncthreads();
        for (int r = 0; r < cnt; ++r) {
            float vc = rows[r][col];
#pragma unroll
            for (int i = 0; i < 16; ++i)
                acc[i] += rows[r][rg * 16 + i] * vc;
        }
    }
#pragma unroll
    for (int i = 0; i < 16; ++i)
        atomicAdd(&h64[(rg * 16 + i) * 64 + col], acc[i]);
}

// o = h64.flat @ Wl + bl ; softmax -> out[10]
__global__ void final_kernel(const float* __restrict__ h64, const float* __restrict__ Wl,
                             const float* __restrict__ bl, float* __restrict__ out) {
    __shared__ float red[256];
    __shared__ float o[10];
    const int tid = threadIdx.x;
    float acc[10];
#pragma unroll
    for (int k = 0; k < 10; ++k) acc[k] = 0.f;
    for (int i = tid; i < 4096; i += 256) {
        float v = h64[i];
#pragma unroll
        for (int k = 0; k < 10; ++k) acc[k] += v * Wl[i * 10 + k];
    }
    for (int k = 0; k < 10; ++k) {
        red[tid] = acc[k];
        __syncthreads();
        for (int s = 128; s > 0; s >>= 1) {
            if (tid < s) red[tid] += red[tid + s];
            __syncthreads();
        }
        if (tid == 0) o[k] = red[0] + bl[k];
        __syncthreads();
    }
    if (tid == 0) {
        float m = o[0];
        for (int k = 1; k < 10; ++k) m = fmaxf(m, o[k]);
        float s = 0.f, e[10];
        for (int k = 0; k < 10; ++k) { e[k] = expf(o[k] - m); s += e[k]; }
        for (int k = 0; k < 10; ++k) out[k] = e[k] / s;
    }
}

extern "C" void kernel_launch(void* const* d_in, const int* in_sizes, int n_in,
                              void* d_out, int out_size, void* d_ws, size_t ws_size,
                              hipStream_t stream) {
    const float* x   = (const float*)d_in[0];
    const int*   ei  = (const int*)d_in[1];
    const float* Wa1 = (const float*)d_in[2];
    const float* ba1 = (const float*)d_in[3];
    const float* Wa2 = (const float*)d_in[4];
    const float* ba2 = (const float*)d_in[5];
    const float* Wl  = (const float*)d_in[6];
    const float* bl  = (const float*)d_in[7];
    float* out = (float*)d_out;

    const int N = in_sizes[0] / 128;
    const int E = in_sizes[1] / 2;
    const int* src = ei;
    const int* dst = ei + E;
    const int NB = (N + BUCKET_SZ - 1) >> BUCKET_SHIFT;  // 391

    // --- workspace layout ---
    // region0 (union): bedges [NB*CAP uint2 = 32MB]  |  bufH+bufA [51.2MB]
    char* wsb = (char*)d_ws;
    float* bufH   = (float*)wsb;
    float* bufA   = bufH + (size_t)N * 64;
    uint2* bedges = (uint2*)wsb;  // dead after bucket_place, before first gemm
    char*  tail   = wsb + (size_t)N * 128 * 4;  // 51.2MB (>= 32.03MB bedges)
    float* dinv   = (float*)tail;               tail += (size_t)N * 4;
    float* h64    = (float*)tail;               tail += 4096 * 4;
    int*   counts = (int*)tail;                 tail += (size_t)N * 4;
    int*   rowptr = (int*)tail;                 tail += (size_t)N * 4;
    int*   rowend = (int*)tail;                 tail += (size_t)N * 4;
    int*   bcnt   = (int*)tail;                 tail += (size_t)NB * 4;
    int*   btot   = (int*)tail;                 tail += 512 * 4;
    int*   ssorted= (int*)tail;                 tail += (size_t)E * 4;

    const int gE = (E + 255) / 256;

    // --- CSR build (bucketed) ---
    hipMemsetAsync(bcnt, 0, (size_t)NB * 4, stream);
    bucket_scatter<<<gE, 256, 0, stream>>>(src, dst, bcnt, bedges, E);
    bucket_count_scan<<<NB, 256, 0, stream>>>(bcnt, bedges, counts, dinv, rowptr, btot, N);
    scan_btot<<<1, 512, 0, stream>>>(btot, NB);
    bucket_place<<<NB, 256, 0, stream>>>(bcnt, bedges, btot, counts, rowptr, rowend, ssorted, N);

    // --- layer 1 ---
    gemm_tiled<128><<<(N + 63) / 64, 256, 0, stream>>>(x, Wa1, bufH, N);
    agg_csr<<<(N + 3) / 4, 256, 0, stream>>>(rowptr, rowend, ssorted, dinv, bufH, ba1, bufA, N);

    // --- layer 2 ---
    gemm_tiled<64><<<(N + 63) / 64, 256, 0, stream>>>(bufA, Wa2, bufH, N);
    agg_csr<<<(N + 3) / 4, 256, 0, stream>>>(rowptr, rowend, ssorted, dinv, bufH, ba2, bufA, N);

    // --- readout ---
    hipMemsetAsync(h64, 0, 4096 * sizeof(float), stream);
    outer_reduce<<<512, 256, 0, stream>>>(bufA, h64, N);
    final_kernel<<<1, 256, 0, stream>>>(h64, Wl, bl, out);
}

// Round 5
// 708.850 us; speedup vs baseline: 2.2363x; 2.2363x over previous
//
#include <hip/hip_runtime.h>

// ---------------------------------------------------------------------------
// PiNet: 2x GCNConv + a2^T a2 readout + linear + softmax
// N=100000, E=3200000, D0=128, D1=D2=64, OUT=10
// R4: back to 100k-cursor CSR build (R3's 391-cursor bucketing serialized on
//     atomic contention: 1107us). New: XCD-sliced scatter — blockIdx%8 group g
//     handles only dst in slice g, so ssorted writes stay in one XCD's L2
//     (write amp ~1x instead of 15x across non-coherent L2s).
// ---------------------------------------------------------------------------

#define SCAN_B 1024

__global__ void hist_dst(const int* __restrict__ dst, int* __restrict__ counts, int E) {
    int e = blockIdx.x * blockDim.x + threadIdx.x;
    if (e < E) atomicAdd(&counts[dst[e]], 1);
}

// exclusive scan, level A: per-block scan of counts -> rowptr, block totals -> bsums
__global__ void scanA(const int* __restrict__ counts, int* __restrict__ rowptr,
                      int* __restrict__ bsums, int N) {
    __shared__ int sh[SCAN_B];
    const int tid = threadIdx.x;
    const int i   = blockIdx.x * SCAN_B + tid;
    int c = (i < N) ? counts[i] : 0;
    sh[tid] = c;
    __syncthreads();
    for (int off = 1; off < SCAN_B; off <<= 1) {
        int t = (tid >= off) ? sh[tid - off] : 0;
        __syncthreads();
        sh[tid] += t;
        __syncthreads();
    }
    if (i < N) rowptr[i] = sh[tid] - c;  // exclusive
    if (tid == SCAN_B - 1) bsums[blockIdx.x] = sh[tid];
}

// level B: exclusive scan of block sums (nb <= 1024), single block
__global__ void scanB(int* __restrict__ bsums, int nb) {
    __shared__ int sh[SCAN_B];
    const int tid = threadIdx.x;
    if (tid < nb) sh[tid] = bsums[tid];
    __syncthreads();
    if (tid == 0) {
        int run = 0;
        for (int k = 0; k < nb; ++k) { int v = sh[k]; sh[k] = run; run += v; }
    }
    __syncthreads();
    if (tid < nb) bsums[tid] = sh[tid];
}

// level C: add block offsets; init cursor = rowptr; dinv = rsqrt(deg+1)
__global__ void scanC(int* __restrict__ rowptr, const int* __restrict__ bsums,
                      const int* __restrict__ counts, int* __restrict__ cursor,
                      float* __restrict__ dinv, int N) {
    int i = blockIdx.x * blockDim.x + threadIdx.x;
    if (i < N) {
        int rp = rowptr[i] + bsums[i >> 10];
        rowptr[i] = rp;
        cursor[i] = rp;
        dinv[i]   = rsqrtf((float)counts[i] + 1.0f);  // +1 self-loop
    }
}

// XCD-sliced scatter: group g = blockIdx%8 handles dst in [g*slice,(g+1)*slice).
// Each group streams the whole edge list (L3-resident after first group);
// its ssorted writes land in one contiguous 1.6MB window -> L2-local, amp ~1x.
__global__ __launch_bounds__(256) void xcd_scatter(const int* __restrict__ src,
                                                   const int* __restrict__ dst,
                                                   int* __restrict__ cursor,
                                                   int* __restrict__ ssorted,
                                                   int E, int slice) {
    const int g   = blockIdx.x & 7;
    const int lo  = g * slice;
    const int hi  = lo + slice;
    const int bg  = blockIdx.x >> 3;
    const int nbg = gridDim.x >> 3;
    const int stride = nbg * 256;
    for (int e = bg * 256 + threadIdx.x; e < E; e += stride) {
        int d = dst[e];
        if (d >= lo && d < hi) {
            int pos = atomicAdd(&cursor[d], 1);
            ssorted[pos] = src[e];
        }
    }
}

// ---------------------------------------------------------------------------
// Register-tiled GEMM: H[n][c] = sum_k A[n][k]*W[k][c], c in [0,64).
// 64 nodes x 64 cols per 256-thread block; each thread computes 4 nodes x 4 cols.
// ---------------------------------------------------------------------------
template <int K>
__global__ __launch_bounds__(256) void gemm_tiled(const float* __restrict__ A,
                                                  const float* __restrict__ W,
                                                  float* __restrict__ H, int N) {
    constexpr int KC = 32;
    __shared__ float xs[64][KC + 4];
    __shared__ float ws[KC][64];
    const int tid  = threadIdx.x;
    const int tx   = tid & 15;
    const int ty   = tid >> 4;
    const int base = blockIdx.x * 64;

    float acc[4][4] = {{0.f}};

    for (int kc = 0; kc < K; kc += KC) {
        for (int idx = tid; idx < 512; idx += 256) {
            int node = idx >> 3, k4 = idx & 7;
            int n = base + node;
            float4 v = make_float4(0.f, 0.f, 0.f, 0.f);
            if (n < N) v = *(const float4*)&A[(long long)n * K + kc + k4 * 4];
            *(float4*)&xs[node][k4 * 4] = v;
        }
        for (int idx = tid; idx < 512; idx += 256) {
            int k = idx >> 4, c4 = idx & 15;
            *(float4*)&ws[k][c4 * 4] = *(const float4*)&W[(long long)(kc + k) * 64 + c4 * 4];
        }
        __syncthreads();

#pragma unroll
        for (int k = 0; k < KC; k += 4) {
            float4 xv[4], wv[4];
#pragma unroll
            for (int i = 0; i < 4; ++i) xv[i] = *(const float4*)&xs[ty * 4 + i][k];
#pragma unroll
            for (int j = 0; j < 4; ++j) wv[j] = *(const float4*)&ws[k + j][tx * 4];
#pragma unroll
            for (int i = 0; i < 4; ++i) {
                float xi[4] = {xv[i].x, xv[i].y, xv[i].z, xv[i].w};
#pragma unroll
                for (int j = 0; j < 4; ++j) {
                    acc[i][0] += xi[j] * wv[j].x;
                    acc[i][1] += xi[j] * wv[j].y;
                    acc[i][2] += xi[j] * wv[j].z;
                    acc[i][3] += xi[j] * wv[j].w;
                }
            }
        }
        __syncthreads();
    }

#pragma unroll
    for (int i = 0; i < 4; ++i) {
        int n = base + ty * 4 + i;
        if (n < N) {
            float4 r = make_float4(acc[i][0], acc[i][1], acc[i][2], acc[i][3]);
            *(float4*)&H[(long long)n * 64 + tx * 4] = r;
        }
    }
}

// CSR aggregation, fused bias + self-loop. One wave per node.
__global__ void agg_csr(const int* __restrict__ rowptr, const int* __restrict__ endptr,
                        const int* __restrict__ ssorted, const float* __restrict__ dinv,
                        const float* __restrict__ H, const float* __restrict__ bias,
                        float* __restrict__ out, int N) {
    const int wid  = (int)(((long long)blockIdx.x * blockDim.x + threadIdx.x) >> 6);
    if (wid >= N) return;
    const int lane = threadIdx.x & 63;
    const int g    = lane >> 4;
    const int fl   = lane & 15;
    const float4* __restrict__ Hv = (const float4*)H;

    const int   n   = wid;
    const float dn  = dinv[n];
    const int   beg = rowptr[n];
    const int   end = endptr[n];

    float4 acc = make_float4(0.f, 0.f, 0.f, 0.f);
    for (int e = beg + g; e < end; e += 4) {
        int    s  = ssorted[e];
        float  w  = dinv[s] * dn;
        float4 hv = Hv[(long long)s * 16 + fl];
        acc.x += w * hv.x; acc.y += w * hv.y; acc.z += w * hv.z; acc.w += w * hv.w;
    }
    acc.x += __shfl_xor(acc.x, 16); acc.y += __shfl_xor(acc.y, 16);
    acc.z += __shfl_xor(acc.z, 16); acc.w += __shfl_xor(acc.w, 16);
    acc.x += __shfl_xor(acc.x, 32); acc.y += __shfl_xor(acc.y, 32);
    acc.z += __shfl_xor(acc.z, 32); acc.w += __shfl_xor(acc.w, 32);

    if (g == 0) {
        float4 selfv = Hv[(long long)n * 16 + fl];
        float4 bv    = ((const float4*)bias)[fl];
        float  w0    = dn * dn;
        float4 res;
        res.x = bv.x + w0 * selfv.x + acc.x;
        res.y = bv.y + w0 * selfv.y + acc.y;
        res.z = bv.z + w0 * selfv.z + acc.z;
        res.w = bv.w + w0 * selfv.w + acc.w;
        ((float4*)out)[(long long)n * 16 + fl] = res;
    }
}

// h64[r][c] += sum_n A2[n][r] * A2[n][c]
__global__ void outer_reduce(const float* __restrict__ A2, float* __restrict__ h64, int N) {
    __shared__ float rows[8][64];
    const int tid = threadIdx.x;
    const int col = tid & 63;
    const int rg  = tid >> 6;
    float acc[16];
#pragma unroll
    for (int i = 0; i < 16; ++i) acc[i] = 0.f;

    int npb   = (N + gridDim.x - 1) / gridDim.x;
    int start = blockIdx.x * npb;
    int end   = min(start + npb, N);
    for (int nb = start; nb < end; nb += 8) {
        int cnt = min(8, end - nb);
        __syncthreads();
        for (int idx = tid; idx < cnt * 64; idx += 256)
            rows[idx >> 6][idx & 63] = A2[(long long)(nb + (idx >> 6)) * 64 + (idx & 63)];
        __syncthreads();
        for (int r = 0; r < cnt; ++r) {
            float vc = rows[r][col];
#pragma unroll
            for (int i = 0; i < 16; ++i)
                acc[i] += rows[r][rg * 16 + i] * vc;
        }
    }
#pragma unroll
    for (int i = 0; i < 16; ++i)
        atomicAdd(&h64[(rg * 16 + i) * 64 + col], acc[i]);
}

// o = h64.flat @ Wl + bl ; softmax -> out[10]
__global__ void final_kernel(const float* __restrict__ h64, const float* __restrict__ Wl,
                             const float* __restrict__ bl, float* __restrict__ out) {
    __shared__ float red[256];
    __shared__ float o[10];
    const int tid = threadIdx.x;
    float acc[10];
#pragma unroll
    for (int k = 0; k < 10; ++k) acc[k] = 0.f;
    for (int i = tid; i < 4096; i += 256) {
        float v = h64[i];
#pragma unroll
        for (int k = 0; k < 10; ++k) acc[k] += v * Wl[i * 10 + k];
    }
    for (int k = 0; k < 10; ++k) {
        red[tid] = acc[k];
        __syncthreads();
        for (int s = 128; s > 0; s >>= 1) {
            if (tid < s) red[tid] += red[tid + s];
            __syncthreads();
        }
        if (tid == 0) o[k] = red[0] + bl[k];
        __syncthreads();
    }
    if (tid == 0) {
        float m = o[0];
        for (int k = 1; k < 10; ++k) m = fmaxf(m, o[k]);
        float s = 0.f, e[10];
        for (int k = 0; k < 10; ++k) { e[k] = expf(o[k] - m); s += e[k]; }
        for (int k = 0; k < 10; ++k) out[k] = e[k] / s;
    }
}

extern "C" void kernel_launch(void* const* d_in, const int* in_sizes, int n_in,
                              void* d_out, int out_size, void* d_ws, size_t ws_size,
                              hipStream_t stream) {
    const float* x   = (const float*)d_in[0];
    const int*   ei  = (const int*)d_in[1];
    const float* Wa1 = (const float*)d_in[2];
    const float* ba1 = (const float*)d_in[3];
    const float* Wa2 = (const float*)d_in[4];
    const float* ba2 = (const float*)d_in[5];
    const float* Wl  = (const float*)d_in[6];
    const float* bl  = (const float*)d_in[7];
    float* out = (float*)d_out;

    const int N = in_sizes[0] / 128;
    const int E = in_sizes[1] / 2;
    const int* src = ei;
    const int* dst = ei + E;
    const int slice = (N + 7) / 8;

    char* wsb = (char*)d_ws;
    float* bufH   = (float*)wsb;                       wsb += (size_t)N * 64 * 4;
    float* bufA   = (float*)wsb;                       wsb += (size_t)N * 64 * 4;
    float* dinv   = (float*)wsb;                       wsb += (size_t)N * 4;
    float* h64    = (float*)wsb;                       wsb += 4096 * 4;
    int*   counts = (int*)wsb;                         wsb += (size_t)N * 4;
    int*   rowptr = (int*)wsb;                         wsb += (size_t)N * 4;
    int*   cursor = (int*)wsb;                         wsb += (size_t)N * 4;
    int*   bsums  = (int*)wsb;                         wsb += 1024 * 4;
    int*   ssorted= (int*)wsb;                         wsb += (size_t)E * 4;

    const int gN = (N + 255) / 256;
    const int gE = (E + 255) / 256;
    const int nb = (N + SCAN_B - 1) / SCAN_B;

    // --- CSR build ---
    hipMemsetAsync(counts, 0, (size_t)N * 4, stream);
    hist_dst<<<gE, 256, 0, stream>>>(dst, counts, E);
    scanA<<<nb, SCAN_B, 0, stream>>>(counts, rowptr, bsums, N);
    scanB<<<1, SCAN_B, 0, stream>>>(bsums, nb);
    scanC<<<gN, 256, 0, stream>>>(rowptr, bsums, counts, cursor, dinv, N);
    xcd_scatter<<<8 * 160, 256, 0, stream>>>(src, dst, cursor, ssorted, E, slice);

    // --- layer 1 ---
    gemm_tiled<128><<<(N + 63) / 64, 256, 0, stream>>>(x, Wa1, bufH, N);
    agg_csr<<<(N + 3) / 4, 256, 0, stream>>>(rowptr, cursor, ssorted, dinv, bufH, ba1, bufA, N);

    // --- layer 2 ---
    gemm_tiled<64><<<(N + 63) / 64, 256, 0, stream>>>(bufA, Wa2, bufH, N);
    agg_csr<<<(N + 3) / 4, 256, 0, stream>>>(rowptr, cursor, ssorted, dinv, bufH, ba2, bufA, N);

    // --- readout ---
    hipMemsetAsync(h64, 0, 4096 * sizeof(float), stream);
    outer_reduce<<<512, 256, 0, stream>>>(bufA, h64, N);
    final_kernel<<<1, 256, 0, stream>>>(h64, Wl, bl, out);
}